// Round 2
// baseline (656.533 us; speedup 1.0000x reference)
//
#include <hip/hip_runtime.h>
#include <math.h>

typedef unsigned short u16;
typedef __attribute__((ext_vector_type(8))) short s16x8;
typedef __attribute__((ext_vector_type(4))) float f32x4;

#define NB 8
#define NT 256
#define NL 24
#define NC 512
#define NH 8
#define ND 64
#define NR (NB*NT*NL)        // 49152 rows
#define NBT (NB*NT)          // 2048

__device__ __forceinline__ u16 f2bf(float f) {
    unsigned u = __float_as_uint(f);
    u = (u + 0x7fffu + ((u >> 16) & 1u)) >> 16;
    return (u16)u;
}
__device__ __forceinline__ float bf2f(u16 h) {
    return __uint_as_float(((unsigned)h) << 16);
}

// ---------------------------------------------------------------------------
// Kernel 1: convert inputs to bf16, transpose weights to [N][K] bf16,
//           precompute tanh(v_init).
// ---------------------------------------------------------------------------
__global__ void convert_kernel(const float* __restrict__ q, const float* __restrict__ kv,
                               const float* __restrict__ Wq, const float* __restrict__ Wkv,
                               const float* __restrict__ Wg, const float* __restrict__ Wm,
                               const float* __restrict__ v_init,
                               u16* __restrict__ qbf, u16* __restrict__ kvbf,
                               u16* __restrict__ Wq_t, u16* __restrict__ Wkv_t,
                               u16* __restrict__ Wg_t, u16* __restrict__ Wm_t,
                               float* __restrict__ tvi)
{
    const int stride = gridDim.x * blockDim.x;
    const int t0 = blockIdx.x * blockDim.x + threadIdx.x;

    const long long n4 = (long long)NR * NC / 4;   // 6,291,456 float4 groups
    for (long long i = t0; i < n4; i += stride) {
        float4 a = ((const float4*)q)[i];
        ushort4 oa;
        oa.x = f2bf(a.x); oa.y = f2bf(a.y); oa.z = f2bf(a.z); oa.w = f2bf(a.w);
        ((ushort4*)qbf)[i] = oa;
        float4 b = ((const float4*)kv)[i];
        ushort4 ob;
        ob.x = f2bf(b.x); ob.y = f2bf(b.y); ob.z = f2bf(b.z); ob.w = f2bf(b.w);
        ((ushort4*)kvbf)[i] = ob;
    }
    // Wq, Wg, Wm: [512][512] -> transposed [n][k]
    for (int e = t0; e < 512 * 512; e += stride) {
        int n = e >> 9, k = e & 511;
        Wq_t[e] = f2bf(Wq[k * 512 + n]);
        Wg_t[e] = f2bf(Wg[k * 512 + n]);
        Wm_t[e] = f2bf(Wm[k * 512 + n]);
    }
    // Wkv: [512][1024] -> transposed [n<1024][k<512]
    for (int e = t0; e < 1024 * 512; e += stride) {
        int n = e >> 9, k = e & 511;
        Wkv_t[e] = f2bf(Wkv[k * 1024 + n]);
    }
    // tanh(v_init): [24][512]
    for (int e = t0; e < NL * NC; e += stride) {
        tvi[e] = tanhf(v_init[e]);
    }
}

// ---------------------------------------------------------------------------
// GEMM: C[M,N] = A[M,K=512] * Bt[N,K=512]^T (+bias, + mode-specific epilogue)
// 128x128 tile, BK=32, 4 waves, global_load_lds staging, 16x16x32 bf16 MFMA.
// MODE 0: out bf16 (qp)            MODE 1: out bf16 (kvp, ldo=1024)
// MODE 2: relu(sigmoid(acc+b)*tvi) -> bf16   MODE 3: acc+b+shortcut -> f32
// ---------------------------------------------------------------------------
template <int MODE>
__global__ __launch_bounds__(256)
void gemm_kernel(const u16* __restrict__ A, int lda,
                 const u16* __restrict__ Bt,
                 const float* __restrict__ bias,
                 void* __restrict__ out, int ldo,
                 const float* __restrict__ extra)
{
    __shared__ __align__(16) u16 Alds[128 * 32];
    __shared__ __align__(16) u16 Blds[128 * 32];

    const int tid = threadIdx.x;
    const int mb = blockIdx.x, nb = blockIdx.y;
    const int wave = tid >> 6, lane = tid & 63;
    const int wr = wave >> 1, wc = wave & 1;
    const int lrow = lane & 15;
    const int lko = (lane >> 4) * 8;     // k-element offset within row

    f32x4 acc[4][4] = {};

    for (int k0 = 0; k0 < 512; k0 += 32) {
        __syncthreads();
        // stage A tile: 512 chunks of 16B; chunk ch -> row=ch>>2, k8=(ch&3)*8
#pragma unroll
        for (int c = 0; c < 2; ++c) {
            int ch = c * 256 + tid;
            int row = ch >> 2, k8 = (ch & 3) * 8;
            const u16* src = A + (size_t)(mb * 128 + row) * lda + k0 + k8;
            u16* dst = &Alds[(c * 256 + wave * 64) * 8];  // wave-uniform base
            __builtin_amdgcn_global_load_lds(
                (const __attribute__((address_space(1))) void*)src,
                (__attribute__((address_space(3))) void*)dst, 16, 0, 0);
        }
#pragma unroll
        for (int c = 0; c < 2; ++c) {
            int ch = c * 256 + tid;
            int row = ch >> 2, k8 = (ch & 3) * 8;
            const u16* src = Bt + (size_t)(nb * 128 + row) * 512 + k0 + k8;
            u16* dst = &Blds[(c * 256 + wave * 64) * 8];
            __builtin_amdgcn_global_load_lds(
                (const __attribute__((address_space(1))) void*)src,
                (__attribute__((address_space(3))) void*)dst, 16, 0, 0);
        }
        asm volatile("s_waitcnt vmcnt(0)" ::: "memory");
        __syncthreads();

        s16x8 af[4], bfr[4];
#pragma unroll
        for (int m = 0; m < 4; ++m)
            af[m] = *(const s16x8*)&Alds[(wr * 64 + m * 16 + lrow) * 32 + lko];
#pragma unroll
        for (int n = 0; n < 4; ++n)
            bfr[n] = *(const s16x8*)&Blds[(wc * 64 + n * 16 + lrow) * 32 + lko];
#pragma unroll
        for (int m = 0; m < 4; ++m)
#pragma unroll
            for (int n = 0; n < 4; ++n)
                acc[m][n] = __builtin_amdgcn_mfma_f32_16x16x32_bf16(
                    af[m], bfr[n], acc[m][n], 0, 0, 0);
    }

    // epilogue: C/D layout col=lane&15, row=(lane>>4)*4+j
    const int rbase = mb * 128 + wr * 64;
    const int cbase = nb * 128 + wc * 64;
#pragma unroll
    for (int m = 0; m < 4; ++m) {
#pragma unroll
        for (int n = 0; n < 4; ++n) {
            int row0 = rbase + m * 16 + ((lane >> 4) * 4);
            int col = cbase + n * 16 + (lane & 15);
            float bv = bias[col];
#pragma unroll
            for (int j = 0; j < 4; ++j) {
                int row = row0 + j;
                float v = acc[m][n][j] + bv;
                if constexpr (MODE == 0 || MODE == 1) {
                    ((u16*)out)[(size_t)row * ldo + col] = f2bf(v);
                } else if constexpr (MODE == 2) {
                    float g = 1.f / (1.f + __expf(-v));
                    float tv = extra[(row % NL) * NC + col];
                    ((u16*)out)[(size_t)row * ldo + col] = f2bf(fmaxf(g * tv, 0.f));
                } else {
                    float sc = extra[(size_t)row * NC + col];
                    ((float*)out)[(size_t)row * ldo + col] = v + sc;
                }
            }
        }
    }
}

// ---------------------------------------------------------------------------
// Attention: one block per (b*t, head). l2norm q/k/v head slices, 24x24
// softmax attention, write x (bf16).
// ---------------------------------------------------------------------------
__global__ __launch_bounds__(256)
void attn_kernel(const u16* __restrict__ qp, const u16* __restrict__ kvp,
                 const u16* __restrict__ vun, u16* __restrict__ xout)
{
    __shared__ float qs[24][65], ks[24][65], vs[24][65];
    __shared__ float Sm[24][25];
    __shared__ float nq[24], nk[24], nv[24];

    const int bt = blockIdx.x, h = blockIdx.y;
    const int tid = threadIdx.x;
    const size_t rowbase = (size_t)bt * NL;

    for (int idx = tid; idx < NL * ND; idx += 256) {
        int r = idx >> 6, c = idx & 63;
        qs[r][c] = bf2f(qp[(rowbase + r) * 512 + h * 64 + c]);
        ks[r][c] = bf2f(kvp[(rowbase + r) * 1024 + h * 64 + c]);
        vs[r][c] = bf2f(vun[(rowbase + r) * 512 + h * 64 + c]);
    }
    __syncthreads();

    if (tid < 72) {
        int m = tid / 24, r = tid % 24;
        float s = 0.f;
        if (m == 0)      for (int c = 0; c < 64; ++c) { float x = qs[r][c]; s += x * x; }
        else if (m == 1) for (int c = 0; c < 64; ++c) { float x = ks[r][c]; s += x * x; }
        else             for (int c = 0; c < 64; ++c) { float x = vs[r][c]; s += x * x; }
        float inv = 1.f / fmaxf(sqrtf(s), 1e-12f);
        if (m == 0) nq[r] = inv; else if (m == 1) nk[r] = inv; else nv[r] = inv;
    }
    __syncthreads();

    // scale v rows in place
    for (int idx = tid; idx < NL * ND; idx += 256) {
        int r = idx >> 6, c = idx & 63;
        vs[r][c] *= nv[r];
    }
    // S = (qh . kh) * nq * nk / 8
    for (int e = tid; e < 24 * 24; e += 256) {
        int qi = e / 24, ki = e % 24;
        float s = 0.f;
        for (int c = 0; c < 64; ++c) s += qs[qi][c] * ks[ki][c];
        Sm[qi][ki] = s * nq[qi] * nk[ki] * 0.125f;
    }
    __syncthreads();

    if (tid < 24) {
        float mx = -1e30f;
        for (int k = 0; k < 24; ++k) mx = fmaxf(mx, Sm[tid][k]);
        float sum = 0.f;
        for (int k = 0; k < 24; ++k) {
            float e = __expf(Sm[tid][k] - mx);
            Sm[tid][k] = e; sum += e;
        }
        float inv = 1.f / sum;
        for (int k = 0; k < 24; ++k) Sm[tid][k] *= inv;
    }
    __syncthreads();

    for (int idx = tid; idx < NL * ND; idx += 256) {
        int qi = idx >> 6, c = idx & 63;
        float s = 0.f;
        for (int k = 0; k < 24; ++k) s += Sm[qi][k] * vs[k][c];
        xout[(rowbase + qi) * 512 + h * 64 + c] = f2bf(s);
    }
}

// ---------------------------------------------------------------------------
extern "C" void kernel_launch(void* const* d_in, const int* in_sizes, int n_in,
                              void* d_out, int out_size, void* d_ws, size_t ws_size,
                              hipStream_t stream)
{
    const float* q      = (const float*)d_in[0];
    const float* kv     = (const float*)d_in[1];
    const float* Wq     = (const float*)d_in[2];
    const float* bq     = (const float*)d_in[3];
    const float* Wkv    = (const float*)d_in[4];
    const float* bkv    = (const float*)d_in[5];
    const float* Wg     = (const float*)d_in[6];
    const float* bg     = (const float*)d_in[7];
    const float* v_init = (const float*)d_in[8];
    const float* Wm     = (const float*)d_in[9];
    const float* bm     = (const float*)d_in[10];

    char* ws = (char*)d_ws;
    const size_t SZ = (size_t)NR * NC;            // 25,165,824 elements
    u16* buf0   = (u16*)(ws);                      // qbf, later reused for x
    u16* buf1   = (u16*)(ws + 2 * SZ);             // kvbf, later reused for v_unnorm
    u16* qp     = (u16*)(ws + 4 * SZ);
    u16* kvp    = (u16*)(ws + 6 * SZ);             // [R,1024]
    char* wbase = ws + 10 * SZ;
    u16* Wq_t   = (u16*)(wbase);
    u16* Wkv_t  = (u16*)(wbase + 512 * 512 * 2);
    u16* Wg_t   = (u16*)(wbase + 512 * 512 * 2 + 1024 * 512 * 2);
    u16* Wm_t   = (u16*)(wbase + 2 * 512 * 512 * 2 + 1024 * 512 * 2);
    float* tvi  = (float*)(wbase + 3 * 512 * 512 * 2 + 1024 * 512 * 2);

    convert_kernel<<<1024, 256, 0, stream>>>(q, kv, Wq, Wkv, Wg, Wm, v_init,
                                             buf0, buf1, Wq_t, Wkv_t, Wg_t, Wm_t, tvi);

    // kvp = kv @ Wkv + bkv   [R,1024] bf16
    gemm_kernel<1><<<dim3(NR / 128, 8), 256, 0, stream>>>(buf1, 512, Wkv_t, bkv,
                                                          kvp, 1024, nullptr);
    // qp = q @ Wq + bq       [R,512] bf16
    gemm_kernel<0><<<dim3(NR / 128, 4), 256, 0, stream>>>(buf0, 512, Wq_t, bq,
                                                          qp, 512, nullptr);
    // v_un = relu(sigmoid(v_lin @ Wg + bg) * tanh(v_init))  -> buf1 (kvbf dead)
    gemm_kernel<2><<<dim3(NR / 128, 4), 256, 0, stream>>>(kvp + 512, 1024, Wg_t, bg,
                                                          buf1, 512, tvi);
    // attention -> x into buf0 (qbf dead)
    attn_kernel<<<dim3(NBT, NH), 256, 0, stream>>>(qp, kvp, buf1, buf0);

    // out = x @ Wm + bm + q  (f32)
    gemm_kernel<3><<<dim3(NR / 128, 4), 256, 0, stream>>>(buf0, 512, Wm_t, bm,
                                                          d_out, 512, q);
}

// Round 5
// 591.726 us; speedup vs baseline: 1.1095x; 1.1095x over previous
//
#include <hip/hip_runtime.h>
#include <math.h>

typedef unsigned short u16;
typedef __attribute__((ext_vector_type(8))) short s16x8;
typedef __attribute__((ext_vector_type(4))) float f32x4;

#define NB 8
#define NT 256
#define NL 24
#define NC 512
#define NH 8
#define ND 64
#define NR (NB*NT*NL)        // 49152 rows
#define NBT (NB*NT)          // 2048

__device__ __forceinline__ u16 f2bf(float f) {
    unsigned u = __float_as_uint(f);
    u = (u + 0x7fffu + ((u >> 16) & 1u)) >> 16;
    return (u16)u;
}
__device__ __forceinline__ float bf2f(u16 h) {
    return __uint_as_float(((unsigned)h) << 16);
}

// ---------------------------------------------------------------------------
// Kernel 1: convert inputs to bf16, transpose weights to [N][K] bf16,
//           precompute tanh(v_init).
// ---------------------------------------------------------------------------
__global__ void convert_kernel(const float* __restrict__ q, const float* __restrict__ kv,
                               const float* __restrict__ Wq, const float* __restrict__ Wkv,
                               const float* __restrict__ Wg, const float* __restrict__ Wm,
                               const float* __restrict__ v_init,
                               u16* __restrict__ qbf, u16* __restrict__ kvbf,
                               u16* __restrict__ Wq_t, u16* __restrict__ Wkv_t,
                               u16* __restrict__ Wg_t, u16* __restrict__ Wm_t,
                               float* __restrict__ tvi)
{
    const int stride = gridDim.x * blockDim.x;
    const int t0 = blockIdx.x * blockDim.x + threadIdx.x;

    const long long n4 = (long long)NR * NC / 4;
    for (long long i = t0; i < n4; i += stride) {
        float4 a = ((const float4*)q)[i];
        ushort4 oa;
        oa.x = f2bf(a.x); oa.y = f2bf(a.y); oa.z = f2bf(a.z); oa.w = f2bf(a.w);
        ((ushort4*)qbf)[i] = oa;
        float4 b = ((const float4*)kv)[i];
        ushort4 ob;
        ob.x = f2bf(b.x); ob.y = f2bf(b.y); ob.z = f2bf(b.z); ob.w = f2bf(b.w);
        ((ushort4*)kvbf)[i] = ob;
    }
    for (int e = t0; e < 512 * 512; e += stride) {
        int n = e >> 9, k = e & 511;
        Wq_t[e] = f2bf(Wq[k * 512 + n]);
        Wg_t[e] = f2bf(Wg[k * 512 + n]);
        Wm_t[e] = f2bf(Wm[k * 512 + n]);
    }
    for (int e = t0; e < 1024 * 512; e += stride) {
        int n = e >> 9, k = e & 511;
        Wkv_t[e] = f2bf(Wkv[k * 1024 + n]);
    }
    for (int e = t0; e < NL * NC; e += stride) {
        tvi[e] = tanhf(v_init[e]);
    }
}

// ---------------------------------------------------------------------------
// GEMM: C[M,N] = A[M,K=512] * Bt[N,K=512]^T (+bias, + mode-specific epilogue)
// 128x128 tile, BK=32, 4 waves, double-buffered LDS (T3-minimum 2-phase):
//   prologue STAGE(b0); vmcnt(0); barrier;
//   loop: STAGE(next) ; ds_read+MFMA(cur) ; vmcnt(0) ; s_barrier
// ---------------------------------------------------------------------------
template <int MODE>
__global__ __launch_bounds__(256)
void gemm_kernel(const u16* __restrict__ A, int lda,
                 const u16* __restrict__ Bt,
                 const float* __restrict__ bias,
                 void* __restrict__ out, int ldo,
                 const float* __restrict__ extra)
{
    __shared__ __align__(16) u16 Alds[2][128 * 32];
    __shared__ __align__(16) u16 Blds[2][128 * 32];

    const int tid = threadIdx.x;
    const int mb = blockIdx.x, nb = blockIdx.y;
    const int wave = tid >> 6, lane = tid & 63;
    const int wr = wave >> 1, wc = wave & 1;
    const int lrow = lane & 15;
    const int lko = (lane >> 4) * 8;

    f32x4 acc[4][4] = {};

    // per-thread staging addresses (chunk ch = c*256+tid -> row=ch>>2, k8=(ch&3)*8)
    const int row_a[2] = { tid >> 2, (256 + tid) >> 2 };
    const int k8_a = (tid & 3) * 8;

#define STAGE(buf, k0)                                                          \
    do {                                                                        \
        _Pragma("unroll")                                                       \
        for (int c = 0; c < 2; ++c) {                                           \
            const u16* srcA = A + (size_t)(mb * 128 + row_a[c]) * lda + (k0) + k8_a; \
            u16* dstA = &Alds[buf][(c * 256 + wave * 64) * 8];                  \
            __builtin_amdgcn_global_load_lds(                                   \
                (const __attribute__((address_space(1))) void*)srcA,            \
                (__attribute__((address_space(3))) void*)dstA, 16, 0, 0);       \
        }                                                                       \
        _Pragma("unroll")                                                       \
        for (int c = 0; c < 2; ++c) {                                           \
            const u16* srcB = Bt + (size_t)(nb * 128 + row_a[c]) * 512 + (k0) + k8_a; \
            u16* dstB = &Blds[buf][(c * 256 + wave * 64) * 8];                  \
            __builtin_amdgcn_global_load_lds(                                   \
                (const __attribute__((address_space(1))) void*)srcB,            \
                (__attribute__((address_space(3))) void*)dstB, 16, 0, 0);       \
        }                                                                       \
    } while (0)

    STAGE(0, 0);
    asm volatile("s_waitcnt vmcnt(0)" ::: "memory");
    __builtin_amdgcn_s_barrier();

    int cur = 0;
#pragma unroll
    for (int t = 0; t < 16; ++t) {
        if (t < 15) STAGE(cur ^ 1, (t + 1) * 32);

        s16x8 af[4], bfr[4];
#pragma unroll
        for (int m = 0; m < 4; ++m)
            af[m] = *(const s16x8*)&Alds[cur][(wr * 64 + m * 16 + lrow) * 32 + lko];
#pragma unroll
        for (int n = 0; n < 4; ++n)
            bfr[n] = *(const s16x8*)&Blds[cur][(wc * 64 + n * 16 + lrow) * 32 + lko];
#pragma unroll
        for (int m = 0; m < 4; ++m)
#pragma unroll
            for (int n = 0; n < 4; ++n)
                acc[m][n] = __builtin_amdgcn_mfma_f32_16x16x32_bf16(
                    af[m], bfr[n], acc[m][n], 0, 0, 0);

        asm volatile("s_waitcnt vmcnt(0)" ::: "memory");
        __builtin_amdgcn_s_barrier();
        cur ^= 1;
    }
#undef STAGE

    // epilogue: C/D layout col=lane&15, row=(lane>>4)*4+j
    const int rbase = mb * 128 + wr * 64;
    const int cbase = nb * 128 + wc * 64;
#pragma unroll
    for (int m = 0; m < 4; ++m) {
#pragma unroll
        for (int n = 0; n < 4; ++n) {
            int row0 = rbase + m * 16 + ((lane >> 4) * 4);
            int col = cbase + n * 16 + (lane & 15);
            float bv = bias[col];
#pragma unroll
            for (int j = 0; j < 4; ++j) {
                int row = row0 + j;
                float v = acc[m][n][j] + bv;
                if constexpr (MODE == 0 || MODE == 1) {
                    ((u16*)out)[(size_t)row * ldo + col] = f2bf(v);
                } else if constexpr (MODE == 2) {
                    float g = 1.f / (1.f + __expf(-v));
                    float tv = extra[(row % NL) * NC + col];
                    ((u16*)out)[(size_t)row * ldo + col] = f2bf(fmaxf(g * tv, 0.f));
                } else {
                    float sc = extra[(size_t)row * NC + col];
                    ((float*)out)[(size_t)row * ldo + col] = v + sc;
                }
            }
        }
    }
}

// ---------------------------------------------------------------------------
// MFMA attention: block = 4 waves, one (b,t) per block, each wave does 2 heads.
// Per head (one wave, no cross-wave sync):
//   - Q/K/V fragments loaded directly from global in MFMA A/B layout
//   - row norms via in-register shfl_xor reduce
//   - S = QK^T (8 mfma), scale by nq*nk/8, 16-lane shfl softmax
//   - P (bf16) and normalized V^T bounced through per-wave LDS
//   - X = P V (8 mfma), scatter-store bf16
// ---------------------------------------------------------------------------
__global__ __launch_bounds__(256)
void attn_kernel(const u16* __restrict__ qp, const u16* __restrict__ kvp,
                 const u16* __restrict__ vun, u16* __restrict__ xout)
{
    __shared__ __align__(16) u16 Plds[4][32 * 32];   // [row<32][k<32] per wave
    __shared__ __align__(16) u16 VTlds[4][64 * 32];  // [c<64][k<32]  per wave

    const int tid = threadIdx.x;
    const int wave = tid >> 6, lane = tid & 63;
    const int lr = lane & 15, lg = lane >> 4;
    const size_t rowbase = (size_t)blockIdx.x * NL;
    u16* P  = Plds[wave];
    u16* VT = VTlds[wave];

    for (int hh = 0; hh < 2; ++hh) {
        const int h = wave * 2 + hh;

        // ---- load fragments (rows clamped to 23: avoids OOB + inf in pad rows)
        s16x8 qf[2][2], kf[2][2], vf[2][2];
#pragma unroll
        for (int m = 0; m < 2; ++m) {
            int rq = m * 16 + lr; int r = rq > 23 ? 23 : rq;
            const u16* q_ = qp  + (rowbase + r) * 512  + h * 64 + lg * 8;
            const u16* k_ = kvp + (rowbase + r) * 1024 + h * 64 + lg * 8;
            const u16* v_ = vun + (rowbase + r) * 512  + h * 64 + lg * 8;
#pragma unroll
            for (int ks = 0; ks < 2; ++ks) {
                qf[m][ks] = *(const s16x8*)(q_ + ks * 32);
                kf[m][ks] = *(const s16x8*)(k_ + ks * 32);
                vf[m][ks] = *(const s16x8*)(v_ + ks * 32);
            }
        }

        // ---- row norms: lane l holds rows (m*16 + lr); 4 lane-groups hold
        //      disjoint 16-elem chunks -> xor16+xor32 gives full row ssq.
        float invq[2], invk[2], invv[2];
#pragma unroll
        for (int m = 0; m < 2; ++m) {
            float sq = 0.f, sk = 0.f, sv = 0.f;
#pragma unroll
            for (int ks = 0; ks < 2; ++ks)
#pragma unroll
                for (int j = 0; j < 8; ++j) {
                    float a = bf2f((u16)qf[m][ks][j]); sq += a * a;
                    float b = bf2f((u16)kf[m][ks][j]); sk += b * b;
                    float c = bf2f((u16)vf[m][ks][j]); sv += c * c;
                }
            sq += __shfl_xor(sq, 16); sq += __shfl_xor(sq, 32);
            sk += __shfl_xor(sk, 16); sk += __shfl_xor(sk, 32);
            sv += __shfl_xor(sv, 16); sv += __shfl_xor(sv, 32);
            invq[m] = 1.f / fmaxf(sqrtf(sq), 1e-12f);
            invk[m] = 1.f / fmaxf(sqrtf(sk), 1e-12f);
            invv[m] = 1.f / fmaxf(sqrtf(sv), 1e-12f);
        }

        // ---- S = Q K^T
        f32x4 sc[2][2] = {};
#pragma unroll
        for (int m = 0; m < 2; ++m)
#pragma unroll
            for (int n = 0; n < 2; ++n)
#pragma unroll
                for (int ks = 0; ks < 2; ++ks)
                    sc[m][n] = __builtin_amdgcn_mfma_f32_16x16x32_bf16(
                        qf[m][ks], kf[n][ks], sc[m][n], 0, 0, 0);

        // ---- scale + softmax (row r = m*16 + lg*4 + j, cols = lr / 16+lr)
#pragma unroll
        for (int m = 0; m < 2; ++m) {
#pragma unroll
            for (int j = 0; j < 4; ++j) {
                float nq = __shfl(invq[m], lg * 4 + j);
                float a0 = sc[m][0][j] * nq * invk[0] * 0.125f;
                float a1 = (lr < 8) ? sc[m][1][j] * nq * invk[1] * 0.125f : -3.0e38f;
                float mx = fmaxf(a0, a1);
#pragma unroll
                for (int d = 1; d < 16; d <<= 1) mx = fmaxf(mx, __shfl_xor(mx, d));
                float e0 = __expf(a0 - mx);
                float e1 = (lr < 8) ? __expf(a1 - mx) : 0.f;
                float s = e0 + e1;
#pragma unroll
                for (int d = 1; d < 16; d <<= 1) s += __shfl_xor(s, d);
                float inv = 1.f / s;
                int r = m * 16 + lg * 4 + j;
                P[r * 32 + lr]      = f2bf(e0 * inv);
                P[r * 32 + 16 + lr] = f2bf(e1 * inv);   // cols 24-31 get 0
            }
        }

        // ---- normalized V^T into LDS: V[r][c] -> VT[c*32 + r]
#pragma unroll
        for (int m = 0; m < 2; ++m)
#pragma unroll
            for (int ks = 0; ks < 2; ++ks)
#pragma unroll
                for (int j = 0; j < 8; ++j) {
                    int c = ks * 32 + lg * 8 + j;
                    int r = m * 16 + lr;
                    VT[c * 32 + r] = f2bf(bf2f((u16)vf[m][ks][j]) * invv[m]);
                }

        asm volatile("s_waitcnt lgkmcnt(0)" ::: "memory");
        __builtin_amdgcn_sched_barrier(0);

        // ---- X = P V
        s16x8 pa[2], vb[4];
#pragma unroll
        for (int m = 0; m < 2; ++m)
            pa[m] = *(const s16x8*)&P[(m * 16 + lr) * 32 + lg * 8];
#pragma unroll
        for (int n = 0; n < 4; ++n)
            vb[n] = *(const s16x8*)&VT[(n * 16 + lr) * 32 + lg * 8];

        f32x4 xa[2][4] = {};
#pragma unroll
        for (int m = 0; m < 2; ++m)
#pragma unroll
            for (int n = 0; n < 4; ++n)
                xa[m][n] = __builtin_amdgcn_mfma_f32_16x16x32_bf16(
                    pa[m], vb[n], xa[m][n], 0, 0, 0);

        // ---- store rows < 24
#pragma unroll
        for (int m = 0; m < 2; ++m)
#pragma unroll
            for (int n = 0; n < 4; ++n)
#pragma unroll
                for (int j = 0; j < 4; ++j) {
                    int r = m * 16 + lg * 4 + j;
                    if (r < 24)
                        xout[(rowbase + r) * 512 + h * 64 + n * 16 + lr] =
                            f2bf(xa[m][n][j]);
                }

        // wave-local LDS reuse across heads: in-order DS pipe + compiler waits
        asm volatile("s_waitcnt lgkmcnt(0)" ::: "memory");
        __builtin_amdgcn_sched_barrier(0);
    }
}

// ---------------------------------------------------------------------------
extern "C" void kernel_launch(void* const* d_in, const int* in_sizes, int n_in,
                              void* d_out, int out_size, void* d_ws, size_t ws_size,
                              hipStream_t stream)
{
    const float* q      = (const float*)d_in[0];
    const float* kv     = (const float*)d_in[1];
    const float* Wq     = (const float*)d_in[2];
    const float* bq     = (const float*)d_in[3];
    const float* Wkv    = (const float*)d_in[4];
    const float* bkv    = (const float*)d_in[5];
    const float* Wg     = (const float*)d_in[6];
    const float* bg     = (const float*)d_in[7];
    const float* v_init = (const float*)d_in[8];
    const float* Wm     = (const float*)d_in[9];
    const float* bm     = (const float*)d_in[10];

    char* ws = (char*)d_ws;
    const size_t SZ = (size_t)NR * NC;
    u16* buf0   = (u16*)(ws);                      // qbf -> later x
    u16* buf1   = (u16*)(ws + 2 * SZ);             // kvbf -> later v_unnorm
    u16* qp     = (u16*)(ws + 4 * SZ);
    u16* kvp    = (u16*)(ws + 6 * SZ);             // [R,1024]
    char* wbase = ws + 10 * SZ;
    u16* Wq_t   = (u16*)(wbase);
    u16* Wkv_t  = (u16*)(wbase + 512 * 512 * 2);
    u16* Wg_t   = (u16*)(wbase + 512 * 512 * 2 + 1024 * 512 * 2);
    u16* Wm_t   = (u16*)(wbase + 2 * 512 * 512 * 2 + 1024 * 512 * 2);
    float* tvi  = (float*)(wbase + 3 * 512 * 512 * 2 + 1024 * 512 * 2);

    convert_kernel<<<1024, 256, 0, stream>>>(q, kv, Wq, Wkv, Wg, Wm, v_init,
                                             buf0, buf1, Wq_t, Wkv_t, Wg_t, Wm_t, tvi);

    gemm_kernel<1><<<dim3(NR / 128, 8), 256, 0, stream>>>(buf1, 512, Wkv_t, bkv,
                                                          kvp, 1024, nullptr);
    gemm_kernel<0><<<dim3(NR / 128, 4), 256, 0, stream>>>(buf0, 512, Wq_t, bq,
                                                          qp, 512, nullptr);
    gemm_kernel<2><<<dim3(NR / 128, 4), 256, 0, stream>>>(kvp + 512, 1024, Wg_t, bg,
                                                          buf1, 512, tvi);

    attn_kernel<<<dim3(NBT), 256, 0, stream>>>(qp, kvp, buf1, buf0);

    gemm_kernel<3><<<dim3(NR / 128, 4), 256, 0, stream>>>(buf0, 512, Wm_t, bm,
                                                          d_out, 512, q);
}